// Round 1
// baseline (6615.549 us; speedup 1.0000x reference)
//
#include <hip/hip_runtime.h>
#include <hip/hip_bf16.h>

// InputAttnEncoder: B=512 independent attention-gated LSTM sequences, T=256 steps.
// Strategy: 256 persistent blocks, 2 batch rows each, full T loop in-kernel.
// Weights converted once per launch to bf16 and swizzled [tile64][kchunk][lane][8]
// so a wave's 16B/lane loads are fully coalesced. fp32 accumulation.

#define Bb 512
#define Tt 256
#define Ff 128
#define Hh 256

// chunk (ushort8) bases within workspace
#define CH_A1 0            // attn1_W: Npad=320 (5 tiles), K=640 (80 chunks)  -> 5*80*64 = 25600
#define CH_A2 25600        // attn2_W: N=128 (2 tiles),  Kpad=264 (33 chunks) -> 2*33*64 = 4224
#define CH_IH 29824        // W_ih:    N=1024 (16 tiles), K=128 (16 chunks)   -> 16*16*64 = 16384
#define CH_HH 46208        // W_hh:    N=1024 (16 tiles), K=256 (32 chunks)   -> 16*32*64 = 32768
#define CH_TOTAL 78976     // * 16B = 1,263,616 bytes of d_ws

typedef unsigned short ushort_t;
typedef ushort_t ushort8 __attribute__((ext_vector_type(8)));

__device__ inline ushort_t f2b_rn(float f) {
    unsigned u = __float_as_uint(f);
    unsigned r = (u + 0x7fffu + ((u >> 16) & 1u)) >> 16;  // round-to-nearest-even
    return (ushort_t)r;
}
__device__ inline float b2f(ushort_t u) {
    return __uint_as_float(((unsigned)u) << 16);
}

__global__ void conv_kernel(const float* __restrict__ a1,  // [257][640]
                            const float* __restrict__ a2,  // [128][257]
                            const float* __restrict__ ih,  // [1024][128]
                            const float* __restrict__ hh,  // [1024][256]
                            ushort_t* __restrict__ ws) {
    int idx = blockIdx.x * 256 + threadIdx.x;
    if (idx >= CH_TOTAL) return;
    int lane = idx & 63;
    float vals[8];
    if (idx < CH_A2) {                       // attn1_W, pad rows 257..319 with 0
        int rel = idx;
        int nt = rel / (80 * 64);
        int c  = (rel / 64) % 80;
        int j  = nt * 64 + lane;
        #pragma unroll
        for (int e = 0; e < 8; ++e) {
            int k = c * 8 + e;
            vals[e] = (j < 257) ? a1[j * 640 + k] : 0.f;
        }
    } else if (idx < CH_IH) {                // attn2_W, pad k 257..263 with 0
        int rel = idx - CH_A2;
        int nt = rel / (33 * 64);
        int c  = (rel / 64) % 33;
        int j  = nt * 64 + lane;
        #pragma unroll
        for (int e = 0; e < 8; ++e) {
            int k = c * 8 + e;
            vals[e] = (k < 257) ? a2[j * 257 + k] : 0.f;
        }
    } else if (idx < CH_HH) {                // W_ih
        int rel = idx - CH_IH;
        int nt = rel / (16 * 64);
        int c  = (rel / 64) % 16;
        int j  = nt * 64 + lane;
        #pragma unroll
        for (int e = 0; e < 8; ++e) vals[e] = ih[j * 128 + c * 8 + e];
    } else {                                 // W_hh
        int rel = idx - CH_HH;
        int nt = rel / (32 * 64);
        int c  = (rel / 64) % 32;
        int j  = nt * 64 + lane;
        #pragma unroll
        for (int e = 0; e < 8; ++e) vals[e] = hh[j * 256 + c * 8 + e];
    }
    ushort8 o;
    #pragma unroll
    for (int e = 0; e < 8; ++e) o[e] = f2b_rn(vals[e]);
    ((ushort8*)ws)[idx] = o;
}

__global__ __launch_bounds__(512) void lstm_kernel(
    const float* __restrict__ X,    // [512][256][128]
    const float* __restrict__ b1,   // [257]
    const float* __restrict__ b2,   // [128]
    const float* __restrict__ bih,  // [1024]
    const float* __restrict__ bhh,  // [1024]
    const ushort_t* __restrict__ wsw,
    float* __restrict__ out)        // hs [512][256][256] then cs [512][256][256]
{
    __shared__ float s_z[2][640];    // [x(128) | h(256) | c(256)] per row
    __shared__ float s_a[2][264];    // attn scores (padded to 264, pads = 0)
    __shared__ float s_xi[2][128];
    __shared__ float s_g[2][1024];

    const int tid  = threadIdx.x;
    const int wave = tid >> 6;
    const int lane = tid & 63;
    const int b0   = blockIdx.x * 2;

    const ushort8* __restrict__ W8 = (const ushort8*)wsw;

    // init h = c = 0; zero s_a pads
    for (int i = tid; i < 2 * 512; i += 512) {
        int r = i >> 9, o = i & 511;
        s_z[r][128 + o] = 0.f;
    }
    if (tid < 14) { int r = tid / 7, o = tid % 7; s_a[r][257 + o] = 0.f; }

    float* __restrict__ hs = out;
    float* __restrict__ cs = out + (size_t)Bb * Tt * Hh;

    for (int t = 0; t < Tt; ++t) {
        __syncthreads();  // h,c from previous step ready; safe to overwrite x
        if (tid < 256) {
            int r = tid >> 7, f = tid & 127;
            s_z[r][f] = X[((size_t)(b0 + r) * Tt + t) * Ff + f];
        }
        __syncthreads();  // x ready

        // phase 1a: a_pre = z @ attn1_W.T  (units: 2 rows x 5 tiles, K=640)
        for (int u = wave; u < 10; u += 8) {
            int r = u / 5, jt = u % 5;
            const ushort8* wp = W8 + CH_A1 + (jt * 80) * 64 + lane;
            const float4* sp = (const float4*)&s_z[r][0];
            float a0 = 0.f, a1v = 0.f, a2v = 0.f, a3 = 0.f;
            #pragma unroll 4
            for (int c = 0; c < 80; ++c) {
                ushort8 wv = wp[0]; wp += 64;
                float4 sa = sp[2 * c], sb = sp[2 * c + 1];
                a0 = fmaf(b2f(wv[0]), sa.x, a0);
                a1v = fmaf(b2f(wv[1]), sa.y, a1v);
                a2v = fmaf(b2f(wv[2]), sa.z, a2v);
                a3 = fmaf(b2f(wv[3]), sa.w, a3);
                a0 = fmaf(b2f(wv[4]), sb.x, a0);
                a1v = fmaf(b2f(wv[5]), sb.y, a1v);
                a2v = fmaf(b2f(wv[6]), sb.z, a2v);
                a3 = fmaf(b2f(wv[7]), sb.w, a3);
            }
            float acc = (a0 + a1v) + (a2v + a3);
            int j = jt * 64 + lane;
            if (j < 257) s_a[r][j] = tanhf(acc + b1[j]);
        }
        // phase 1b: gh = h @ W_hh.T + b_ih + b_hh  (units: 2 x 16, K=256)
        for (int u = wave; u < 32; u += 8) {
            int r = u >> 4, jt = u & 15;
            const ushort8* wp = W8 + CH_HH + (jt * 32) * 64 + lane;
            const float4* sp = (const float4*)&s_z[r][128];
            float a0 = 0.f, a1v = 0.f, a2v = 0.f, a3 = 0.f;
            #pragma unroll 4
            for (int c = 0; c < 32; ++c) {
                ushort8 wv = wp[0]; wp += 64;
                float4 sa = sp[2 * c], sb = sp[2 * c + 1];
                a0 = fmaf(b2f(wv[0]), sa.x, a0);
                a1v = fmaf(b2f(wv[1]), sa.y, a1v);
                a2v = fmaf(b2f(wv[2]), sa.z, a2v);
                a3 = fmaf(b2f(wv[3]), sa.w, a3);
                a0 = fmaf(b2f(wv[4]), sb.x, a0);
                a1v = fmaf(b2f(wv[5]), sb.y, a1v);
                a2v = fmaf(b2f(wv[6]), sb.z, a2v);
                a3 = fmaf(b2f(wv[7]), sb.w, a3);
            }
            float acc = (a0 + a1v) + (a2v + a3);
            int g = jt * 64 + lane;
            s_g[r][g] = acc + bih[g] + bhh[g];
        }
        __syncthreads();  // a, gh ready

        // phase 2: xi = (a @ attn2_W.T + b2) * x  (units: 2 x 2, Kpad=264)
        for (int u = wave; u < 4; u += 8) {
            int r = u >> 1, jt = u & 1;
            const ushort8* wp = W8 + CH_A2 + (jt * 33) * 64 + lane;
            const float4* sp = (const float4*)&s_a[r][0];
            float a0 = 0.f, a1v = 0.f, a2v = 0.f, a3 = 0.f;
            #pragma unroll 4
            for (int c = 0; c < 33; ++c) {
                ushort8 wv = wp[0]; wp += 64;
                float4 sa = sp[2 * c], sb = sp[2 * c + 1];
                a0 = fmaf(b2f(wv[0]), sa.x, a0);
                a1v = fmaf(b2f(wv[1]), sa.y, a1v);
                a2v = fmaf(b2f(wv[2]), sa.z, a2v);
                a3 = fmaf(b2f(wv[3]), sa.w, a3);
                a0 = fmaf(b2f(wv[4]), sb.x, a0);
                a1v = fmaf(b2f(wv[5]), sb.y, a1v);
                a2v = fmaf(b2f(wv[6]), sb.z, a2v);
                a3 = fmaf(b2f(wv[7]), sb.w, a3);
            }
            float acc = (a0 + a1v) + (a2v + a3);
            int f = jt * 64 + lane;
            s_xi[r][f] = (acc + b2[f]) * s_z[r][f];
        }
        __syncthreads();  // xi ready

        // phase 3: gates += xi @ W_ih.T  (units: 2 x 16, K=128)
        for (int u = wave; u < 32; u += 8) {
            int r = u >> 4, jt = u & 15;
            const ushort8* wp = W8 + CH_IH + (jt * 16) * 64 + lane;
            const float4* sp = (const float4*)&s_xi[r][0];
            float a0 = 0.f, a1v = 0.f, a2v = 0.f, a3 = 0.f;
            #pragma unroll 4
            for (int c = 0; c < 16; ++c) {
                ushort8 wv = wp[0]; wp += 64;
                float4 sa = sp[2 * c], sb = sp[2 * c + 1];
                a0 = fmaf(b2f(wv[0]), sa.x, a0);
                a1v = fmaf(b2f(wv[1]), sa.y, a1v);
                a2v = fmaf(b2f(wv[2]), sa.z, a2v);
                a3 = fmaf(b2f(wv[3]), sa.w, a3);
                a0 = fmaf(b2f(wv[4]), sb.x, a0);
                a1v = fmaf(b2f(wv[5]), sb.y, a1v);
                a2v = fmaf(b2f(wv[6]), sb.z, a2v);
                a3 = fmaf(b2f(wv[7]), sb.w, a3);
            }
            float acc = (a0 + a1v) + (a2v + a3);
            int g = jt * 64 + lane;
            s_g[r][g] += acc;
        }
        __syncthreads();  // gates ready

        // phase 4: LSTM pointwise + output  (512 items = 1/thread)
        {
            int r = tid >> 8, d = tid & 255;
            float gi = s_g[r][d];
            float gf = s_g[r][d + 256];
            float gg = s_g[r][d + 512];
            float go = s_g[r][d + 768];
            float i_g = 1.f / (1.f + expf(-gi));
            float f_g = 1.f / (1.f + expf(-gf));
            float g_g = tanhf(gg);
            float o_g = 1.f / (1.f + expf(-go));
            float c_old = s_z[r][384 + d];
            float c_new = fmaf(f_g, c_old, i_g * g_g);
            float h_new = o_g * tanhf(c_new);
            s_z[r][128 + d] = h_new;
            s_z[r][384 + d] = c_new;
            size_t oidx = ((size_t)(b0 + r) * Tt + t) * Hh + d;
            hs[oidx] = h_new;
            cs[oidx] = c_new;
        }
    }
}

extern "C" void kernel_launch(void* const* d_in, const int* in_sizes, int n_in,
                              void* d_out, int out_size, void* d_ws, size_t ws_size,
                              hipStream_t stream) {
    const float* X   = (const float*)d_in[0];
    const float* a1W = (const float*)d_in[1];
    const float* a1b = (const float*)d_in[2];
    const float* a2W = (const float*)d_in[3];
    const float* a2b = (const float*)d_in[4];
    const float* Wih = (const float*)d_in[5];
    const float* Whh = (const float*)d_in[6];
    const float* bih = (const float*)d_in[7];
    const float* bhh = (const float*)d_in[8];
    ushort_t* ws = (ushort_t*)d_ws;

    hipLaunchKernelGGL(conv_kernel, dim3((CH_TOTAL + 255) / 256), dim3(256), 0, stream,
                       a1W, a2W, Wih, Whh, ws);
    hipLaunchKernelGGL(lstm_kernel, dim3(256), dim3(512), 0, stream,
                       X, a1b, a2b, bih, bhh, ws, (float*)d_out);
}

// Round 2
// 6473.554 us; speedup vs baseline: 1.0219x; 1.0219x over previous
//
#include <hip/hip_runtime.h>

// InputAttnEncoder round 2: MFMA path.
// 32 blocks x 16 rows, 1024 threads (16 waves). mfma_f32_16x16x32_bf16, M=16=rows.
// Weights prepacked once into B-fragment order [tile16][kc][lane][ushort8].
// Activations converted to bf16 in LDS each step; gate accumulators live in VGPRs
// across the Whh (phase A) and Wih (phase C) matmuls.

#define Bb 512
#define Tt 256
#define Ff 128
#define Hh 256

typedef unsigned short ushort_t;
typedef short s16x8 __attribute__((ext_vector_type(8)));
typedef float f32x4 __attribute__((ext_vector_type(4)));

// prepack geometry (chunk = 64 lanes x 16B)
#define A1_NT 17
#define A1_NK 20
#define A2_NT 8
#define A2_NK 9
#define IH_NT 64
#define IH_NK 4
#define HH_NT 64
#define HH_NK 8
#define CH_A1 0
#define CH_A2 21760            // + 17*20*64
#define CH_IH 26368            // + 8*9*64
#define CH_HH 42752            // + 64*4*64
#define CH_TOTAL 75520         // + 64*8*64   (*16B = 1,208,320 bytes of d_ws)

// LDS pitches (elements)
#define ZP 648    // z row: [x 0..127 | h 128..383 | c 384..639], pad->648 (2-way banks)
#define AP 296    // attn scores row, K padded 257->288, pitch 296
#define XIP 136   // xi row, K=128, pitch 136
#define XP 132    // fp32 x row
#define GP 1028   // fp32 gates row (1024 + 4; 4-bank/row shift -> 2-way on writes)

__device__ inline ushort_t f2b(float f) {
    unsigned u = __float_as_uint(f);
    unsigned r = (u + 0x7fffu + ((u >> 16) & 1u)) >> 16;  // RNE
    return (ushort_t)r;
}
__device__ inline float fast_sig(float x) { return 1.f / (1.f + __expf(-x)); }
__device__ inline float fast_tanh(float x) {
    float cx = fminf(fmaxf(x, -15.f), 15.f);
    float e = __expf(2.f * cx);
    return (e - 1.f) / (e + 1.f);
}

__global__ void conv_kernel(const float* __restrict__ a1,  // [257][640]
                            const float* __restrict__ a2,  // [128][257]
                            const float* __restrict__ ih,  // [1024][128]
                            const float* __restrict__ hh,  // [1024][256]
                            ushort_t* __restrict__ ws) {
    int idx = blockIdx.x * 256 + threadIdx.x;
    if (idx >= CH_TOTAL) return;
    int lane = idx & 63;
    int jo = lane & 15;
    int ko = (lane >> 4) * 8;
    float v[8];
    if (idx < CH_A2) {
        int cix = idx >> 6;
        int tile = cix / A1_NK, kc = cix % A1_NK;
        int j = tile * 16 + jo, k = kc * 32 + ko;
        #pragma unroll
        for (int e = 0; e < 8; ++e) v[e] = (j < 257) ? a1[j * 640 + k + e] : 0.f;
    } else if (idx < CH_IH) {
        int cix = (idx - CH_A2) >> 6;
        int tile = cix / A2_NK, kc = cix % A2_NK;
        int j = tile * 16 + jo, k = kc * 32 + ko;
        #pragma unroll
        for (int e = 0; e < 8; ++e) v[e] = (k + e < 257) ? a2[j * 257 + k + e] : 0.f;
    } else if (idx < CH_HH) {
        int cix = (idx - CH_IH) >> 6;
        int tile = cix / IH_NK, kc = cix % IH_NK;
        int j = tile * 16 + jo, k = kc * 32 + ko;
        #pragma unroll
        for (int e = 0; e < 8; ++e) v[e] = ih[j * 128 + k + e];
    } else {
        int cix = (idx - CH_HH) >> 6;
        int tile = cix / HH_NK, kc = cix % HH_NK;
        int j = tile * 16 + jo, k = kc * 32 + ko;
        #pragma unroll
        for (int e = 0; e < 8; ++e) v[e] = hh[j * 256 + k + e];
    }
    union { s16x8 v8; ushort_t u[8]; } o;
    #pragma unroll
    for (int e = 0; e < 8; ++e) o.u[e] = f2b(v[e]);
    ((s16x8*)ws)[idx] = o.v8;
}

__global__ __launch_bounds__(1024) void lstm_mfma(
    const float* __restrict__ X,    // [512][256][128]
    const float* __restrict__ b1,   // [257]
    const float* __restrict__ b2,   // [128]
    const float* __restrict__ bih,  // [1024]
    const float* __restrict__ bhh,  // [1024]
    const ushort_t* __restrict__ wsw,
    float* __restrict__ out)        // hs [512][256][256] then cs
{
    __shared__ ushort_t z_bf[16][ZP];    // bf16 [x|h|c]
    __shared__ ushort_t a_bf[16][AP];    // bf16 attn scores (K padded w/ zeros)
    __shared__ ushort_t xi_bf[16][XIP];  // bf16 xi
    __shared__ float    s_x[16][XP];     // fp32 x (for gating)
    __shared__ float    s_g[16][GP];     // fp32 gates
    __shared__ float    s_c[16][256];    // fp32 c state

    const int tid = threadIdx.x;
    const int w   = tid >> 6;
    const int l   = tid & 63;
    const int lj  = l & 15;         // tile-col (j) / A-row
    const int lr4 = (l >> 4) * 4;   // D row base
    const int lk8 = (l >> 4) * 8;   // A/B k offset
    const int b0  = blockIdx.x * 16;

    const s16x8* __restrict__ W8 = (const s16x8*)wsw;

    // ---- per-lane bias preloads ----
    float b1v0 = 0.f, b1v1 = 0.f;
    { int j = w * 16 + lj; if (j < 257) b1v0 = b1[j]; }
    if (w == 0) { int j = 256 + lj; if (j < 257) b1v1 = b1[j]; }
    float b2v = 0.f;
    if (w >= 8) b2v = b2[(w - 8) * 16 + lj];
    float bg[4];
    #pragma unroll
    for (int i = 0; i < 4; ++i) { int j = (4 * w + i) * 16 + lj; bg[i] = bih[j] + bhh[j]; }

    // ---- init LDS ----
    for (int i = tid; i < 16 * 512; i += 1024) {           // h,c = 0 (bf16)
        int r = i >> 9, k = i & 511;
        z_bf[r][128 + k] = 0;
    }
    for (int i = tid; i < 16 * AP; i += 1024) {            // attn scores + zero pads
        int r = i / AP, k = i - r * AP;
        a_bf[r][k] = 0;
    }
    for (int i = tid; i < 16 * 256; i += 1024) {           // c = 0 (fp32)
        int r = i >> 8, d = i & 255;
        s_c[r][d] = 0.f;
    }
    if (tid < 512) {                                        // x_0
        int r = tid >> 5, c4 = (tid & 31) * 4;
        float4 xv = *(const float4*)&X[((size_t)(b0 + r) * Tt + 0) * Ff + c4];
        s_x[r][c4] = xv.x; s_x[r][c4 + 1] = xv.y; s_x[r][c4 + 2] = xv.z; s_x[r][c4 + 3] = xv.w;
        z_bf[r][c4] = f2b(xv.x); z_bf[r][c4 + 1] = f2b(xv.y);
        z_bf[r][c4 + 2] = f2b(xv.z); z_bf[r][c4 + 3] = f2b(xv.w);
    }
    __syncthreads();

    float* __restrict__ hs = out;
    float* __restrict__ cs = out + (size_t)Bb * Tt * Hh;

    f32x4 agate[4];

    for (int t = 0; t < Tt; ++t) {
        // ===== Phase A: attn1 (owned tile) + Whh (4 gate tiles, acc in regs) =====
        {
            f32x4 acc = {0.f, 0.f, 0.f, 0.f};
            const s16x8* wp = W8 + CH_A1 + (w * A1_NK) * 64 + l;
            #pragma unroll 4
            for (int kc = 0; kc < A1_NK; ++kc) {
                s16x8 a = *(const s16x8*)&z_bf[lj][kc * 32 + lk8];
                acc = __builtin_amdgcn_mfma_f32_16x16x32_bf16(a, wp[kc * 64], acc, 0, 0, 0);
            }
            int j = w * 16 + lj;
            if (j < 257) {
                #pragma unroll
                for (int q = 0; q < 4; ++q)
                    a_bf[lr4 + q][j] = f2b(fast_tanh(acc[q] + b1v0));
            }
        }
        if (w == 0) {  // attn1 tile 16 (j = 256 only)
            f32x4 acc = {0.f, 0.f, 0.f, 0.f};
            const s16x8* wp = W8 + CH_A1 + (16 * A1_NK) * 64 + l;
            #pragma unroll 4
            for (int kc = 0; kc < A1_NK; ++kc) {
                s16x8 a = *(const s16x8*)&z_bf[lj][kc * 32 + lk8];
                acc = __builtin_amdgcn_mfma_f32_16x16x32_bf16(a, wp[kc * 64], acc, 0, 0, 0);
            }
            int j = 256 + lj;
            if (j < 257) {
                #pragma unroll
                for (int q = 0; q < 4; ++q)
                    a_bf[lr4 + q][j] = f2b(fast_tanh(acc[q] + b1v1));
            }
        }
        {   // Whh
            s16x8 ah[HH_NK];
            #pragma unroll
            for (int kc = 0; kc < HH_NK; ++kc)
                ah[kc] = *(const s16x8*)&z_bf[lj][128 + kc * 32 + lk8];
            #pragma unroll
            for (int i = 0; i < 4; ++i) {
                f32x4 acc = {0.f, 0.f, 0.f, 0.f};
                const s16x8* wp = W8 + CH_HH + ((4 * w + i) * HH_NK) * 64 + l;
                #pragma unroll
                for (int kc = 0; kc < HH_NK; ++kc)
                    acc = __builtin_amdgcn_mfma_f32_16x16x32_bf16(ah[kc], wp[kc * 64], acc, 0, 0, 0);
                agate[i] = acc;
            }
        }
        __syncthreads();  // a_bf ready

        // ===== Phase B: attn2 + gating (waves 8..15) =====
        if (w >= 8) {
            int p = w - 8;
            f32x4 acc = {0.f, 0.f, 0.f, 0.f};
            const s16x8* wp = W8 + CH_A2 + (p * A2_NK) * 64 + l;
            #pragma unroll 3
            for (int kc = 0; kc < A2_NK; ++kc) {
                s16x8 a = *(const s16x8*)&a_bf[lj][kc * 32 + lk8];
                acc = __builtin_amdgcn_mfma_f32_16x16x32_bf16(a, wp[kc * 64], acc, 0, 0, 0);
            }
            int j = p * 16 + lj;
            #pragma unroll
            for (int q = 0; q < 4; ++q) {
                int r = lr4 + q;
                float xi = (acc[q] + b2v) * s_x[r][j];
                xi_bf[r][j] = f2b(xi);
            }
        }
        __syncthreads();  // xi ready

        // ===== Phase C: Wih (accumulate onto agate), write gates =====
        {
            s16x8 ax[IH_NK];
            #pragma unroll
            for (int kc = 0; kc < IH_NK; ++kc)
                ax[kc] = *(const s16x8*)&xi_bf[lj][kc * 32 + lk8];
            #pragma unroll
            for (int i = 0; i < 4; ++i) {
                f32x4 acc = agate[i];
                const s16x8* wp = W8 + CH_IH + ((4 * w + i) * IH_NK) * 64 + l;
                #pragma unroll
                for (int kc = 0; kc < IH_NK; ++kc)
                    acc = __builtin_amdgcn_mfma_f32_16x16x32_bf16(ax[kc], wp[kc * 64], acc, 0, 0, 0);
                int j = (4 * w + i) * 16 + lj;
                #pragma unroll
                for (int q = 0; q < 4; ++q)
                    s_g[lr4 + q][j] = acc[q] + bg[i];
            }
        }
        __syncthreads();  // gates ready

        // ===== Phase D: pointwise LSTM + output + x prefetch =====
        float4 xv;
        int xr = 0, xc = 0;
        bool ldx = (t + 1 < Tt) && (tid < 512);
        if (ldx) {
            xr = tid >> 5; xc = (tid & 31) * 4;
            xv = *(const float4*)&X[((size_t)(b0 + xr) * Tt + (t + 1)) * Ff + xc];
        }
        #pragma unroll
        for (int p4 = 0; p4 < 4; ++p4) {
            int r = p4 * 4 + (tid >> 8);
            int d = tid & 255;
            float gi = s_g[r][d];
            float gf = s_g[r][d + 256];
            float gg = s_g[r][d + 512];
            float go = s_g[r][d + 768];
            float ig = fast_sig(gi);
            float fg = fast_sig(gf);
            float g_g = fast_tanh(gg);
            float og = fast_sig(go);
            float cn = fmaf(fg, s_c[r][d], ig * g_g);
            float hn = og * fast_tanh(cn);
            s_c[r][d] = cn;
            z_bf[r][128 + d] = f2b(hn);
            z_bf[r][384 + d] = f2b(cn);
            size_t oi = ((size_t)(b0 + r) * Tt + t) * Hh + d;
            hs[oi] = hn;
            cs[oi] = cn;
        }
        if (ldx) {
            s_x[xr][xc] = xv.x; s_x[xr][xc + 1] = xv.y; s_x[xr][xc + 2] = xv.z; s_x[xr][xc + 3] = xv.w;
            z_bf[xr][xc] = f2b(xv.x); z_bf[xr][xc + 1] = f2b(xv.y);
            z_bf[xr][xc + 2] = f2b(xv.z); z_bf[xr][xc + 3] = f2b(xv.w);
        }
        __syncthreads();  // state ready for next step
    }
}

extern "C" void kernel_launch(void* const* d_in, const int* in_sizes, int n_in,
                              void* d_out, int out_size, void* d_ws, size_t ws_size,
                              hipStream_t stream) {
    const float* X   = (const float*)d_in[0];
    const float* a1W = (const float*)d_in[1];
    const float* a1b = (const float*)d_in[2];
    const float* a2W = (const float*)d_in[3];
    const float* a2b = (const float*)d_in[4];
    const float* Wih = (const float*)d_in[5];
    const float* Whh = (const float*)d_in[6];
    const float* bih = (const float*)d_in[7];
    const float* bhh = (const float*)d_in[8];
    ushort_t* ws = (ushort_t*)d_ws;

    hipLaunchKernelGGL(conv_kernel, dim3(CH_TOTAL / 256), dim3(256), 0, stream,
                       a1W, a2W, Wih, Whh, ws);
    hipLaunchKernelGGL(lstm_mfma, dim3(32), dim3(1024), 0, stream,
                       X, a1b, a2b, bih, bhh, ws, (float*)d_out);
}